// Round 1
// baseline (162.461 us; speedup 1.0000x reference)
//
#include <hip/hip_runtime.h>
#include <hip/hip_bf16.h>

// Problem constants (from setup_inputs): B=4, N=8192, M=8192, D=3, fp32.
constexpr int B = 4;
constexpr int N = 8192;
constexpr int M = 8192;

constexpr int TN = 256;              // n's per block (one per thread)
constexpr int CHUNKS = 8;            // split of M for occupancy
constexpr int CHUNK = M / CHUNKS;    // 1024 points per block
constexpr int NTILES = N / TN;       // 32

// ---------------------------------------------------------------------------
// Prep: w[b*M+m] = { -2*px, -2*py, -2*pz, px^2+py^2+pz^2 }
// Makes the point-side inner-loop data one aligned float4 per m, which is
// wave-uniform in the main kernel (scalar-load eligible).
// ---------------------------------------------------------------------------
__global__ __launch_bounds__(256) void prep_kernel(const float* __restrict__ point,
                                                   float4* __restrict__ w) {
    int i = blockIdx.x * 256 + threadIdx.x;   // 0 .. B*M-1
    if (i < B * M) {
        float px = point[i * 3 + 0];
        float py = point[i * 3 + 1];
        float pz = point[i * 3 + 2];
        float4 v;
        v.x = -2.0f * px;
        v.y = -2.0f * py;
        v.z = -2.0f * pz;
        v.w = fmaf(px, px, fmaf(py, py, pz * pz));
        w[i] = v;
    }
}

// ---------------------------------------------------------------------------
// Main: one thread per (b, n); each block scans one 1024-point chunk of M.
// t_m = ||p_m||^2 - 2 a.p_m ; running min via min3; final d2 = max(t+||a||^2, 0)
// merged across chunks with atomicMin on the uint view (d2 >= 0 so uint
// ordering == float ordering; out pre-set to 0x7F7F7F7F = 3.4e38f).
// ---------------------------------------------------------------------------
__global__ __launch_bounds__(256) void main_kernel(const float* __restrict__ input,
                                                   const float4* __restrict__ w,
                                                   unsigned int* __restrict__ out) {
    const int bid   = blockIdx.x;
    const int chunk = bid % CHUNKS;
    const int ntile = (bid / CHUNKS) % NTILES;
    const int b     = bid / (CHUNKS * NTILES);
    const int n     = ntile * TN + threadIdx.x;

    const float* a = input + ((size_t)b * N + n) * 3;
    const float a0 = a[0], a1 = a[1], a2 = a[2];
    const float sq_in = fmaf(a0, a0, fmaf(a1, a1, a2 * a2));

    // Wave-uniform pointer into the prepped point data for this chunk.
    const float4* __restrict__ wp = w + (size_t)b * M + (size_t)chunk * CHUNK;

    float r = 1e30f;
#pragma unroll 4
    for (int m = 0; m < CHUNK; m += 2) {
        const float4 w0 = wp[m];
        const float4 w1 = wp[m + 1];
        float t0 = fmaf(w0.x, a0, w0.w);
        t0 = fmaf(w0.y, a1, t0);
        t0 = fmaf(w0.z, a2, t0);
        float t1 = fmaf(w1.x, a0, w1.w);
        t1 = fmaf(w1.y, a1, t1);
        t1 = fmaf(w1.z, a2, t1);
        r = fminf(r, fminf(t0, t1));   // -> v_min3_f32
    }

    float d2 = r + sq_in;
    d2 = fmaxf(d2, 0.0f);
    atomicMin(&out[(size_t)b * N + n], __float_as_uint(d2));
}

// ---------------------------------------------------------------------------
// Fallback (ws too small for the 512 KB prep table): direct difference form,
// same parallel structure, raw point reads.
// ---------------------------------------------------------------------------
__global__ __launch_bounds__(256) void main_noprep(const float* __restrict__ input,
                                                   const float* __restrict__ point,
                                                   unsigned int* __restrict__ out) {
    const int bid   = blockIdx.x;
    const int chunk = bid % CHUNKS;
    const int ntile = (bid / CHUNKS) % NTILES;
    const int b     = bid / (CHUNKS * NTILES);
    const int n     = ntile * TN + threadIdx.x;

    const float* a = input + ((size_t)b * N + n) * 3;
    const float a0 = a[0], a1 = a[1], a2 = a[2];

    const float* __restrict__ pp = point + ((size_t)b * M + (size_t)chunk * CHUNK) * 3;

    float r = 1e30f;
#pragma unroll 4
    for (int m = 0; m < CHUNK; ++m) {
        const float px = pp[m * 3 + 0];
        const float py = pp[m * 3 + 1];
        const float pz = pp[m * 3 + 2];
        const float sq_pt = fmaf(px, px, fmaf(py, py, pz * pz));
        float t = fmaf(-2.0f * px, a0, sq_pt);
        t = fmaf(-2.0f * py, a1, t);
        t = fmaf(-2.0f * pz, a2, t);
        r = fminf(r, t);
    }

    const float sq_in = fmaf(a0, a0, fmaf(a1, a1, a2 * a2));
    float d2 = r + sq_in;
    d2 = fmaxf(d2, 0.0f);
    atomicMin(&out[(size_t)b * N + n], __float_as_uint(d2));
}

extern "C" void kernel_launch(void* const* d_in, const int* in_sizes, int n_in,
                              void* d_out, int out_size, void* d_ws, size_t ws_size,
                              hipStream_t stream) {
    const float* input = (const float*)d_in[0];   // [B, N, 3] fp32
    const float* point = (const float*)d_in[1];   // [B, M, 3] fp32
    unsigned int* out  = (unsigned int*)d_out;    // [B, N] fp32 viewed as uint

    // Init output to a huge positive float (byte-repeatable pattern).
    // 0x7F7F7F7F as float = 3.39e38; uint ordering == float ordering for
    // non-negative floats, so atomicMin(uint) implements float min.
    (void)hipMemsetAsync(d_out, 0x7F, (size_t)out_size * sizeof(float), stream);

    const size_t w_bytes = (size_t)B * M * sizeof(float4);
    const int main_grid = B * NTILES * CHUNKS;   // 1024 blocks

    if (ws_size >= w_bytes) {
        float4* w = (float4*)d_ws;
        const int prep_grid = (B * M + 255) / 256;   // 128 blocks
        prep_kernel<<<prep_grid, 256, 0, stream>>>(point, w);
        main_kernel<<<main_grid, 256, 0, stream>>>(input, w, out);
    } else {
        main_noprep<<<main_grid, 256, 0, stream>>>(input, point, out);
    }
}

// Round 2
// 89.070 us; speedup vs baseline: 1.8240x; 1.8240x over previous
//
#include <hip/hip_runtime.h>
#include <hip/hip_bf16.h>

// Problem constants (from setup_inputs): B=4, N=8192, M=8192, D=3, fp32.
constexpr int B = 4;
constexpr int N = 8192;
constexpr int M = 8192;

constexpr int TN = 256;              // threads per block
constexpr int NQ = 4;                // queries per thread (registers)
constexpr int QB = TN * NQ;          // 1024 queries per block
constexpr int NTILES = N / QB;       // 8
constexpr int CHUNKS = 32;           // split of M for occupancy
constexpr int CHUNK = M / CHUNKS;    // 256 points per block

// ---------------------------------------------------------------------------
// Prep: w[b*M+m] = { -2*px, -2*py, -2*pz, ||p||^2 }  (one aligned float4/m,
// wave-uniform in main -> scalar loads). Also initializes the output to the
// byte-pattern 0x7F7F7F7F (3.39e38f): for non-negative floats, uint ordering
// == float ordering, so atomicMin(uint) implements float min. B*M == B*N here
// so the same grid covers both writes.
// ---------------------------------------------------------------------------
__global__ __launch_bounds__(256) void prep_kernel(const float* __restrict__ point,
                                                   float4* __restrict__ w,
                                                   unsigned int* __restrict__ out) {
    int i = blockIdx.x * 256 + threadIdx.x;   // 0 .. B*M-1
    if (i < B * M) {
        float px = point[i * 3 + 0];
        float py = point[i * 3 + 1];
        float pz = point[i * 3 + 2];
        float4 v;
        v.x = -2.0f * px;
        v.y = -2.0f * py;
        v.z = -2.0f * pz;
        v.w = fmaf(px, px, fmaf(py, py, pz * pz));
        w[i] = v;
    }
    if (i < B * N) {
        out[i] = 0x7F7F7F7Fu;
    }
}

// ---------------------------------------------------------------------------
// Main: each thread owns NQ=4 queries (a-vectors + running mins in registers);
// each block scans one 256-point chunk. Per 2 points: 2 wave-uniform float4
// scalar loads amortized over 4 queries -> 28 VALU ops per 8 pairs.
// t_m = ||p_m||^2 - 2 a.p_m ; final d2 = max(t + ||a||^2, 0), merged across
// chunks with atomicMin on the uint view.
// ---------------------------------------------------------------------------
__global__ __launch_bounds__(256) void main_kernel(const float* __restrict__ input,
                                                   const float4* __restrict__ w,
                                                   unsigned int* __restrict__ out) {
    const int bid   = blockIdx.x;
    const int chunk = bid % CHUNKS;
    const int ntile = (bid / CHUNKS) % NTILES;
    const int b     = bid / (CHUNKS * NTILES);
    const int n0    = ntile * QB + threadIdx.x;   // queries n0 + q*TN

    float a0[NQ], a1[NQ], a2[NQ], r[NQ];
#pragma unroll
    for (int q = 0; q < NQ; ++q) {
        const float* a = input + ((size_t)b * N + n0 + q * TN) * 3;
        a0[q] = a[0];
        a1[q] = a[1];
        a2[q] = a[2];
        r[q]  = 1e30f;
    }

    // Wave-uniform pointer into the prepped point data for this chunk.
    const float4* __restrict__ wp = w + (size_t)b * M + (size_t)chunk * CHUNK;

#pragma unroll 2
    for (int m = 0; m < CHUNK; m += 2) {
        const float4 w0 = wp[m];
        const float4 w1 = wp[m + 1];
#pragma unroll
        for (int q = 0; q < NQ; ++q) {
            float t0 = fmaf(w0.x, a0[q], w0.w);
            t0 = fmaf(w0.y, a1[q], t0);
            t0 = fmaf(w0.z, a2[q], t0);
            float t1 = fmaf(w1.x, a0[q], w1.w);
            t1 = fmaf(w1.y, a1[q], t1);
            t1 = fmaf(w1.z, a2[q], t1);
            r[q] = fminf(r[q], fminf(t0, t1));   // -> v_min3_f32
        }
    }

#pragma unroll
    for (int q = 0; q < NQ; ++q) {
        const float sq_in = fmaf(a0[q], a0[q], fmaf(a1[q], a1[q], a2[q] * a2[q]));
        float d2 = fmaxf(r[q] + sq_in, 0.0f);
        atomicMin(&out[(size_t)b * N + n0 + q * TN], __float_as_uint(d2));
    }
}

extern "C" void kernel_launch(void* const* d_in, const int* in_sizes, int n_in,
                              void* d_out, int out_size, void* d_ws, size_t ws_size,
                              hipStream_t stream) {
    const float* input = (const float*)d_in[0];   // [B, N, 3] fp32
    const float* point = (const float*)d_in[1];   // [B, M, 3] fp32
    unsigned int* out  = (unsigned int*)d_out;    // [B, N] fp32 viewed as uint

    float4* w = (float4*)d_ws;                    // 512 KB prep table
    const int prep_grid = (B * M + 255) / 256;    // 128 blocks
    const int main_grid = B * NTILES * CHUNKS;    // 1024 blocks

    prep_kernel<<<prep_grid, 256, 0, stream>>>(point, w, out);
    main_kernel<<<main_grid, 256, 0, stream>>>(input, w, out);
}

// Round 3
// 83.674 us; speedup vs baseline: 1.9416x; 1.0645x over previous
//
#include <hip/hip_runtime.h>
#include <hip/hip_bf16.h>

// Problem constants (from setup_inputs): B=4, N=8192, M=8192, D=3, fp32.
constexpr int B = 4;
constexpr int N = 8192;
constexpr int M = 8192;

constexpr int TN = 256;              // threads per block
constexpr int NQ = 4;                // queries per thread (registers)
constexpr int QB = TN * NQ;          // 1024 queries per block
constexpr int NTILES = N / QB;       // 8
constexpr int CHUNKS = 64;           // split of M -> grid 2048 = 8 blocks/CU
constexpr int CHUNK = M / CHUNKS;    // 128 points per block

// ---------------------------------------------------------------------------
// Prep: w[b*M+m] = { -2*px, -2*py, -2*pz, ||p||^2 }  (one aligned float4/m,
// wave-uniform in main -> scalar s_load_dwordx4). Also initializes the output
// to byte-pattern 0x7F7F7F7F (3.39e38f): for non-negative floats uint ordering
// == float ordering, so atomicMin(uint) implements float min. B*M == B*N so
// one grid covers both writes.
// ---------------------------------------------------------------------------
__global__ __launch_bounds__(256) void prep_kernel(const float* __restrict__ point,
                                                   float4* __restrict__ w,
                                                   unsigned int* __restrict__ out) {
    int i = blockIdx.x * 256 + threadIdx.x;   // 0 .. B*M-1
    if (i < B * M) {
        float px = point[i * 3 + 0];
        float py = point[i * 3 + 1];
        float pz = point[i * 3 + 2];
        float4 v;
        v.x = -2.0f * px;
        v.y = -2.0f * py;
        v.z = -2.0f * pz;
        v.w = fmaf(px, px, fmaf(py, py, pz * pz));
        w[i] = v;
    }
    if (i < B * N) {
        out[i] = 0x7F7F7F7Fu;
    }
}

// ---------------------------------------------------------------------------
// Main: each thread owns NQ=4 queries in registers; each block scans one
// 128-point chunk. Per iteration: 4 wave-uniform float4 scalar loads issued
// together, then 56 VALU ops (48 FMA + 8 min3) covering 16 pairs.
// t_m = ||p_m||^2 - 2 a.p_m ; final d2 = max(t + ||a||^2, 0), merged across
// chunks with atomicMin on the uint view of the output.
// __launch_bounds__(256,8): 8 waves/EU -> VGPR capped at 64, full occupancy.
// ---------------------------------------------------------------------------
__global__ __launch_bounds__(256, 8) void main_kernel(const float* __restrict__ input,
                                                      const float4* __restrict__ w,
                                                      unsigned int* __restrict__ out) {
    const int bid   = blockIdx.x;
    const int chunk = bid % CHUNKS;
    const int ntile = (bid / CHUNKS) % NTILES;
    const int b     = bid / (CHUNKS * NTILES);
    const int n0    = ntile * QB + threadIdx.x;   // queries n0 + q*TN

    float a0[NQ], a1[NQ], a2[NQ], r[NQ];
#pragma unroll
    for (int q = 0; q < NQ; ++q) {
        const float* a = input + ((size_t)b * N + n0 + q * TN) * 3;
        a0[q] = a[0];
        a1[q] = a[1];
        a2[q] = a[2];
        r[q]  = 1e30f;
    }

    // Wave-uniform pointer into the prepped point data for this chunk.
    const float4* __restrict__ wp = w + (size_t)b * M + (size_t)chunk * CHUNK;

    for (int m = 0; m < CHUNK; m += 4) {
        // Issue all four uniform 16B loads before the compute block.
        const float4 w0 = wp[m];
        const float4 w1 = wp[m + 1];
        const float4 w2 = wp[m + 2];
        const float4 w3 = wp[m + 3];
#pragma unroll
        for (int q = 0; q < NQ; ++q) {
            float t0 = fmaf(w0.x, a0[q], w0.w);
            t0 = fmaf(w0.y, a1[q], t0);
            t0 = fmaf(w0.z, a2[q], t0);
            float t1 = fmaf(w1.x, a0[q], w1.w);
            t1 = fmaf(w1.y, a1[q], t1);
            t1 = fmaf(w1.z, a2[q], t1);
            float t2 = fmaf(w2.x, a0[q], w2.w);
            t2 = fmaf(w2.y, a1[q], t2);
            t2 = fmaf(w2.z, a2[q], t2);
            float t3 = fmaf(w3.x, a0[q], w3.w);
            t3 = fmaf(w3.y, a1[q], t3);
            t3 = fmaf(w3.z, a2[q], t3);
            r[q] = fminf(r[q], fminf(t0, t1));   // -> v_min3_f32
            r[q] = fminf(r[q], fminf(t2, t3));   // -> v_min3_f32
        }
    }

#pragma unroll
    for (int q = 0; q < NQ; ++q) {
        const float sq_in = fmaf(a0[q], a0[q], fmaf(a1[q], a1[q], a2[q] * a2[q]));
        float d2 = fmaxf(r[q] + sq_in, 0.0f);
        atomicMin(&out[(size_t)b * N + n0 + q * TN], __float_as_uint(d2));
    }
}

extern "C" void kernel_launch(void* const* d_in, const int* in_sizes, int n_in,
                              void* d_out, int out_size, void* d_ws, size_t ws_size,
                              hipStream_t stream) {
    const float* input = (const float*)d_in[0];   // [B, N, 3] fp32
    const float* point = (const float*)d_in[1];   // [B, M, 3] fp32
    unsigned int* out  = (unsigned int*)d_out;    // [B, N] fp32 viewed as uint

    float4* w = (float4*)d_ws;                    // 512 KB prep table
    const int prep_grid = (B * M + 255) / 256;    // 128 blocks
    const int main_grid = B * NTILES * CHUNKS;    // 2048 blocks

    prep_kernel<<<prep_grid, 256, 0, stream>>>(point, w, out);
    main_kernel<<<main_grid, 256, 0, stream>>>(input, w, out);
}